// Round 5
// baseline (327.380 us; speedup 1.0000x reference)
//
#include <hip/hip_runtime.h>
#include <hip/hip_bf16.h>

#define B_    2
#define T_    2048
#define C_    2048
#define NH_   16
#define KVH_  4
#define HD_   128
#define QKV_  3072
#define M_    4096

typedef float  floatx4 __attribute__((ext_vector_type(4)));
typedef __bf16 bf16x8  __attribute__((ext_vector_type(8)));
typedef __bf16 bf16x4  __attribute__((ext_vector_type(4)));
typedef __bf16 bf16x2  __attribute__((ext_vector_type(2)));

typedef const __attribute__((address_space(1))) void* gas_t;
typedef __attribute__((address_space(3))) void*       las_t;
__device__ __forceinline__ void gl_lds16(const void* g, void* l) {
  __builtin_amdgcn_global_load_lds((gas_t)g, (las_t)l, 16, 0, 0);
}

// ---------------- fp32 -> bf16 conversion, all three tensors in one launch ----------
__global__ __launch_bounds__(256) void cvt3(const float* __restrict__ s0, __bf16* __restrict__ d0, int n0,
                                            const float* __restrict__ s1, __bf16* __restrict__ d1, int n1,
                                            const float* __restrict__ s2, __bf16* __restrict__ d2, int n2) {
  int i = blockIdx.x * blockDim.x + threadIdx.x;
  const float* s; __bf16* d;
  if (i < n0) { s = s0; d = d0; }
  else {
    i -= n0;
    if (i < n1) { s = s1; d = d1; }
    else { i -= n1; if (i >= n2) return; s = s2; d = d2; }
  }
  float4 f = ((const float4*)s)[i];
  bf16x4 o = { (__bf16)f.x, (__bf16)f.y, (__bf16)f.z, (__bf16)f.w };
  ((bf16x4*)d)[i] = o;
}

// ---------------- C = A[M][K] * B[N][K]^T, templated output dtype ----------------
// m97 structure, BK=64 staged as two BK=32 sub-buffers: 32 MFMAs per sync window.
template <typename OutT>
__global__ __launch_bounds__(256) void gemm_bt(const __bf16* __restrict__ A,
                                               const __bf16* __restrict__ Bm,
                                               OutT* __restrict__ Cc,
                                               int N, int K) {
  __shared__ __align__(16) __bf16 As[2][128 * 32];
  __shared__ __align__(16) __bf16 Bs[2][128 * 32];
  const int tid  = threadIdx.x;
  const int wid  = tid >> 6, lane = tid & 63, quad = lane >> 4, r16 = lane & 15;
  const int bm   = blockIdx.y * 128, bn = blockIdx.x * 128;
  const int wm   = (wid >> 1) * 64, wn = (wid & 1) * 64;
  const int srow = wid * 16 + (lane >> 2);
  const int scol = (lane & 3) * 8;
  const __bf16* aptr = A  + (size_t)(bm + srow) * K + scol;
  const __bf16* bptr = Bm + (size_t)(bn + srow) * K + scol;
  const size_t rowskip = (size_t)64 * K;

  floatx4 acc[4][4];
  #pragma unroll
  for (int i = 0; i < 4; i++)
    #pragma unroll
    for (int j = 0; j < 4; j++) acc[i][j] = (floatx4){0.f, 0.f, 0.f, 0.f};

  for (int k0 = 0; k0 < K; k0 += 64) {
    #pragma unroll
    for (int hf = 0; hf < 2; hf++) {
      gl_lds16(aptr + k0 + hf * 32,           &As[hf][wid * 512]);
      gl_lds16(aptr + rowskip + k0 + hf * 32, &As[hf][2048 + wid * 512]);
      gl_lds16(bptr + k0 + hf * 32,           &Bs[hf][wid * 512]);
      gl_lds16(bptr + rowskip + k0 + hf * 32, &Bs[hf][2048 + wid * 512]);
    }
    __syncthreads();

    #pragma unroll
    for (int hf = 0; hf < 2; hf++) {
      bf16x8 af[4], bfr[4];
      #pragma unroll
      for (int i = 0; i < 4; i++) af[i]  = *(const bf16x8*)&As[hf][(wm + i * 16 + r16) * 32 + quad * 8];
      #pragma unroll
      for (int j = 0; j < 4; j++) bfr[j] = *(const bf16x8*)&Bs[hf][(wn + j * 16 + r16) * 32 + quad * 8];
      #pragma unroll
      for (int i = 0; i < 4; i++)
        #pragma unroll
        for (int j = 0; j < 4; j++)
          acc[i][j] = __builtin_amdgcn_mfma_f32_16x16x32_bf16(af[i], bfr[j], acc[i][j], 0, 0, 0);
    }
    __syncthreads();
  }

  #pragma unroll
  for (int i = 0; i < 4; i++) {
    #pragma unroll
    for (int reg = 0; reg < 4; reg++) {
      int row = bm + wm + i * 16 + quad * 4 + reg;
      OutT* crow = Cc + (size_t)row * N + bn + wn;
      #pragma unroll
      for (int j = 0; j < 4; j++) crow[j * 16 + r16] = (OutT)acc[i][j][reg];
    }
  }
}

// ---------------- RoPE + RMSNorm (bf16 qkv input), one wave per (b,t) row ----------
__global__ __launch_bounds__(256) void rope_norm(const __bf16* __restrict__ qkv,
                                                 const float* __restrict__ qw,
                                                 const float* __restrict__ kw,
                                                 const float* __restrict__ fc,
                                                 const float* __restrict__ fs,
                                                 __bf16* __restrict__ qn,
                                                 __bf16* __restrict__ kn) {
  const int tid  = threadIdx.x;
  const int wid  = tid >> 6, lane = tid & 63;
  const int row  = blockIdx.x * 4 + wid;        // b*T + t
  const int b    = row >> 11, t = row & (T_ - 1);
  const float cs = fc[t * 64 + lane], sn = fs[t * 64 + lane];
  const __bf16* base = qkv + (size_t)row * QKV_;

  #pragma unroll 2
  for (int h = 0; h < NH_; h++) {
    bf16x2 ab = *(const bf16x2*)(base + h * HD_ + 2 * lane);
    float ax = (float)ab[0], ay = (float)ab[1];
    float oa = ax * cs - ay * sn;
    float ob = ax * sn + ay * cs;
    float ss = oa * oa + ob * ob;
    #pragma unroll
    for (int off = 32; off; off >>= 1) ss += __shfl_xor(ss, off);
    float rinv = rsqrtf(ss * (1.0f / HD_) + 1e-6f);
    bf16x2 o = { (__bf16)(oa * rinv * qw[2 * lane]), (__bf16)(ob * rinv * qw[2 * lane + 1]) };
    *(bf16x2*)&qn[(size_t)((b * NH_ + h) * T_ + t) * HD_ + 2 * lane] = o;
  }
  #pragma unroll 2
  for (int h = 0; h < KVH_; h++) {
    bf16x2 ab = *(const bf16x2*)(base + C_ + h * HD_ + 2 * lane);
    float ax = (float)ab[0], ay = (float)ab[1];
    float oa = ax * cs - ay * sn;
    float ob = ax * sn + ay * cs;
    float ss = oa * oa + ob * ob;
    #pragma unroll
    for (int off = 32; off; off >>= 1) ss += __shfl_xor(ss, off);
    float rinv = rsqrtf(ss * (1.0f / HD_) + 1e-6f);
    bf16x2 o = { (__bf16)(oa * rinv * kw[2 * lane]), (__bf16)(ob * rinv * kw[2 * lane + 1]) };
    *(bf16x2*)&kn[(size_t)((b * KVH_ + h) * T_ + t) * HD_ + 2 * lane] = o;
  }
}

// ---------------- V transpose: qkv bf16 [t][d] -> vT bf16 [d][t], 64x64 LDS tiles ----
__global__ __launch_bounds__(256) void vtrans(const __bf16* __restrict__ qkv,
                                              __bf16* __restrict__ vT) {
  __shared__ __bf16 L[64 * 68];
  const int tid = threadIdx.x;
  const int t0 = blockIdx.x * 64;
  const int d0 = blockIdx.y * 64;
  const int z  = blockIdx.z;            // b*KVH + hk
  const int b  = z >> 2, hk = z & 3;
  const int srcc = C_ + KVH_ * HD_ + hk * HD_ + d0;
  const int rr = tid >> 4, c4 = (tid & 15) * 4;
  #pragma unroll
  for (int i = 0; i < 4; i++) {
    int t = rr + i * 16;
    bf16x4 f = *(const bf16x4*)&qkv[(size_t)(b * T_ + t0 + t) * QKV_ + srcc + c4];
    *(bf16x4*)&L[t * 68 + c4] = f;
  }
  __syncthreads();
  const int dr = tid >> 3, tc8 = (tid & 7) * 8;
  #pragma unroll
  for (int i = 0; i < 2; i++) {
    int d = dr + i * 32;
    bf16x8 ov;
    #pragma unroll
    for (int j = 0; j < 8; j++) ov[j] = L[(tc8 + j) * 68 + d];
    *(bf16x8*)&vT[(size_t)(z * HD_ + d0 + d) * T_ + t0 + tc8] = ov;
  }
}

// ---------------- causal flash attention: 512 threads, 8 waves x 16 rows ----------
// Round-5: attack the per-iteration serial spine.  r4's chunked P did the
// exp->write->fence->read->PV round-trip TWICE per K-tile and its stride-48 read
// was 4-way bank-conflicted (conflicts 0.54M -> 2.16M).  Now: ONE full-width P
// [16][64] per wave with a chunk-XOR swizzle (16B chunk c of row r stored at
// slot c ^ (r&7)):
//  - write phase (fixed quad,reg; 16 lanes): 2 chunk slots x 8 lanes -> 2-way, free
//  - read phase (b128, row=r16, chunk=quad / 4+quad): 8 slots x 2 lanes -> free
// One exp/write/read pass per iteration, single 18-MFMA PV cluster under one
// setprio.  LDS = Ks 32K + Vs 32K + Ps 16K = 81920 B exactly -> 2 blocks/CU
// (2 x 80 KiB = the full 160 KiB pool).  Keeps r4's dbuf + single barrier +
// defer-max.  Grid = 512: x<256 heavy tile qt=15-p, x+256 light tile qt=p.
__device__ __forceinline__ int swz_w(int lane) {       // write slot for chunk (kt=lane>>2, ds=lane&3)
  return ((lane & 3) << 4) | ((lane >> 2) ^ ((lane & 3) << 1));
}
__device__ __forceinline__ int swz_r(int quad, int r16) { // read slot for (kt=r16, ds=quad)
  return (quad << 4) | (r16 ^ (quad << 1));
}

__device__ __forceinline__ void kv_prefetch8(const __bf16* kbase, const __bf16* vbase,
                                             int kt0, int wid, int lane,
                                             bf16x8 kreg[2], bf16x8 vreg[2]) {
  const int r4 = lane >> 2, c8 = (lane & 3) * 8;
  #pragma unroll
  for (int i = 0; i < 2; i++) {
    const int n = wid * 2 + i;   // K tile: kt4 = n>>2 (16 kt rows), d4 = n&3 (32 d cols)
    kreg[i] = *(const bf16x8*)&kbase[(size_t)(kt0 + (n >> 2) * 16 + r4) * HD_ + (n & 3) * 32 + c8];
    vreg[i] = *(const bf16x8*)&vbase[(size_t)((n >> 1) * 16 + r4) * T_ + kt0 + (n & 1) * 32 + c8];
  }
}

__device__ __forceinline__ void kv_commit8(__bf16* Ks, __bf16* Vs, int wid, int lane,
                                           const bf16x8 kreg[2], const bf16x8 vreg[2]) {
  const int slot = swz_w(lane);
  #pragma unroll
  for (int i = 0; i < 2; i++) {
    *(bf16x8*)(Ks + (wid * 2 + i) * 512 + slot * 8) = kreg[i];
    *(bf16x8*)(Vs + (wid * 2 + i) * 512 + slot * 8) = vreg[i];
  }
}

__global__ __launch_bounds__(512, 4) void flash(const __bf16* __restrict__ q,
                                                const __bf16* __restrict__ k,
                                                const __bf16* __restrict__ vT,
                                                __bf16* __restrict__ y) {
  __shared__ __align__(16) __bf16 Ks[2][64 * 128];  // dbuf x 16 swizzled tiles [16kt][32d]
  __shared__ __align__(16) __bf16 Vs[2][64 * 128];  // dbuf x 16 swizzled tiles [16d][32kt]
  __shared__ __align__(16) __bf16 Ps[8][16 * 64];   // per-wave P, chunk-XOR swizzled
  const int tid = threadIdx.x;
  const int wid = tid >> 6, lane = tid & 63, quad = lane >> 4, r16 = lane & 15;
  const int x   = blockIdx.x;
  const int p   = (x >> 5) & 7, hl = x & 31;
  const int qt  = (x < 256) ? (15 - p) : p;       // heavy half first; x and x+256 pair on one CU
  const int b = hl >> 4, h = hl & 15, hk = h >> 2;

  const __bf16* kbase = k  + (size_t)(b * KVH_ + hk) * T_ * HD_;
  const __bf16* vbase = vT + (size_t)(b * KVH_ + hk) * HD_ * T_;
  __bf16* Pw = Ps[wid];
  const float sc = 0.08838834764831845f;  // 1/sqrt(128)
  const float NEG = -__builtin_inff();
  bf16x8 ones;
  #pragma unroll
  for (int i = 0; i < 8; i++) ones[i] = (__bf16)1.0f;

  const int nt = 2 * (qt + 1);
  const int r0 = qt * 128 + wid * 16;   // this wave's 16 q-rows

  const __bf16* qrow = q + ((size_t)(b * NH_ + h) * T_ + r0 + r16) * HD_;
  bf16x8 qf[4];
  #pragma unroll
  for (int kb = 0; kb < 4; kb++) qf[kb] = *(const bf16x8*)&qrow[kb * 32 + quad * 8];

  floatx4 o[8], ol = (floatx4){0.f, 0.f, 0.f, 0.f};
  #pragma unroll
  for (int j = 0; j < 8; j++) o[j] = (floatx4){0.f, 0.f, 0.f, 0.f};
  float m_r[4] = {NEG, NEG, NEG, NEG};

  bf16x8 kreg[2], vreg[2];
  kv_prefetch8(kbase, vbase, 0, wid, lane, kreg, vreg);
  kv_commit8(&Ks[0][0], &Vs[0][0], wid, lane, kreg, vreg);
  if (nt > 1) kv_prefetch8(kbase, vbase, 64, wid, lane, kreg, vreg);
  __syncthreads();                        // tile 0 visible

  #pragma unroll 1
  for (int it = 0; it < nt; ++it) {
    if (it + 1 < nt) {
      // buf[(it+1)&1]'s previous readers (tile it-1) finished at the barrier
      // ending iter it-1, so this commit is race-free.
      kv_commit8(&Ks[(it + 1) & 1][0], &Vs[(it + 1) & 1][0], wid, lane, kreg, vreg);
      if (it + 2 < nt) kv_prefetch8(kbase, vbase, (it + 2) * 64, wid, lane, kreg, vreg);
    }

    const int kt0 = it * 64;
    const __bf16* Kb = &Ks[it & 1][0];
    const __bf16* Vb = &Vs[it & 1][0];
    if (kt0 <= r0 + 15) {                 // wave-uniform causal skip (no barriers inside)
      floatx4 s[4];
      #pragma unroll
      for (int cb = 0; cb < 4; cb++) s[cb] = (floatx4){0.f, 0.f, 0.f, 0.f};
      __builtin_amdgcn_s_setprio(1);
      #pragma unroll
      for (int kb = 0; kb < 4; kb++)
        #pragma unroll
        for (int cb = 0; cb < 4; cb++) {
          bf16x8 kf = *(const bf16x8*)&Kb[(cb * 4 + kb) * 512 + swz_r(quad, r16) * 8];
          s[cb] = __builtin_amdgcn_mfma_f32_16x16x32_bf16(qf[kb], kf, s[cb], 0, 0, 0);
        }
      __builtin_amdgcn_s_setprio(0);

      // scale + causal mask in place
      const bool needmask = (kt0 + 63 > r0);  // wave-uniform
      #pragma unroll
      for (int reg = 0; reg < 4; reg++) {
        const int rowq = r0 + quad * 4 + reg;
        s[0][reg] *= sc; s[1][reg] *= sc; s[2][reg] *= sc; s[3][reg] *= sc;
        if (needmask) {
          if (kt0 +      r16 > rowq) s[0][reg] = NEG;
          if (kt0 + 16 + r16 > rowq) s[1][reg] = NEG;
          if (kt0 + 32 + r16 > rowq) s[2][reg] = NEG;
          if (kt0 + 48 + r16 > rowq) s[3][reg] = NEG;
        }
      }
      // per-row max + running-max bookkeeping
      float mx[4], mnew[4];
      #pragma unroll
      for (int reg = 0; reg < 4; reg++) {
        float m0 = fmaxf(fmaxf(s[0][reg], s[1][reg]), fmaxf(s[2][reg], s[3][reg]));
        #pragma unroll
        for (int off = 8; off; off >>= 1) m0 = fmaxf(m0, __shfl_xor(m0, off));
        mx[reg] = m0;
        mnew[reg] = fmaxf(m_r[reg], m0);
      }
      // T13 defer-max: if no row grew its max by >8, keep old m (P bounded by e^8)
      float growth = fmaxf(fmaxf(mx[0] - m_r[0], mx[1] - m_r[1]),
                           fmaxf(mx[2] - m_r[2], mx[3] - m_r[3]));
      if (!__all(growth <= 8.0f)) {
        #pragma unroll
        for (int reg = 0; reg < 4; reg++) {
          float a = __expf(m_r[reg] - mnew[reg]);
          m_r[reg] = mnew[reg];
          ol[reg] *= a;
          #pragma unroll
          for (int j = 0; j < 8; j++) o[j][reg] *= a;
        }
      }
      // exp -> full-width swizzled P -> one P-frag pair -> one PV MFMA cluster
      #pragma unroll
      for (int reg = 0; reg < 4; reg++) {
        const int pr = quad * 4 + reg;
        const int rb = pr & 7;
        const int c0 = r16 >> 3, ce = r16 & 7;
        Pw[pr * 64 + (((c0    ) ^ rb) << 3) + ce] = (__bf16)__expf(s[0][reg] - m_r[reg]);
        Pw[pr * 64 + (((c0 + 2) ^ rb) << 3) + ce] = (__bf16)__expf(s[1][reg] - m_r[reg]);
        Pw[pr * 64 + (((c0 + 4) ^ rb) << 3) + ce] = (__bf16)__expf(s[2][reg] - m_r[reg]);
        Pw[pr * 64 + (((c0 + 6) ^ rb) << 3) + ce] = (__bf16)__expf(s[3][reg] - m_r[reg]);
      }
      __asm__ volatile("" ::: "memory");  // wave-private P: writes before reads
      bf16x8 pf0 = *(const bf16x8*)&Pw[r16 * 64 + (((quad    ) ^ (r16 & 7)) << 3)];
      bf16x8 pf1 = *(const bf16x8*)&Pw[r16 * 64 + (((quad + 4) ^ (r16 & 7)) << 3)];
      __builtin_amdgcn_s_setprio(1);
      ol = __builtin_amdgcn_mfma_f32_16x16x32_bf16(pf0, ones, ol, 0, 0, 0);
      ol = __builtin_amdgcn_mfma_f32_16x16x32_bf16(pf1, ones, ol, 0, 0, 0);
      #pragma unroll
      for (int j = 0; j < 8; j++) {
        bf16x8 vf0 = *(const bf16x8*)&Vb[(j * 2 + 0) * 512 + swz_r(quad, r16) * 8];
        bf16x8 vf1 = *(const bf16x8*)&Vb[(j * 2 + 1) * 512 + swz_r(quad, r16) * 8];
        o[j] = __builtin_amdgcn_mfma_f32_16x16x32_bf16(pf0, vf0, o[j], 0, 0, 0);
        o[j] = __builtin_amdgcn_mfma_f32_16x16x32_bf16(pf1, vf1, o[j], 0, 0, 0);
      }
      __builtin_amdgcn_s_setprio(0);
    }
    __syncthreads();                      // seals tile it reads; publishes tile it+1
  }

  #pragma unroll
  for (int reg = 0; reg < 4; reg++) {
    int trow = r0 + quad * 4 + reg;
    float inv = 1.0f / ol[reg];  // rowsum identical across lanes (ones-MFMA trick)
    __bf16* yr = y + ((size_t)(b * T_) + trow) * C_ + h * HD_;
    #pragma unroll
    for (int j = 0; j < 8; j++) yr[j * 16 + r16] = (__bf16)(o[j][reg] * inv);
  }
}

extern "C" void kernel_launch(void* const* d_in, const int* in_sizes, int n_in,
                              void* d_out, int out_size, void* d_ws, size_t ws_size,
                              hipStream_t stream) {
  const float* x     = (const float*)d_in[0];
  const float* wqkv  = (const float*)d_in[1];
  const float* wproj = (const float*)d_in[2];
  const float* qw    = (const float*)d_in[3];
  const float* kw    = (const float*)d_in[4];
  const float* fc    = (const float*)d_in[5];
  const float* fs    = (const float*)d_in[6];
  float* out = (float*)d_out;

  char* w = (char*)d_ws;
  __bf16* xb     = (__bf16*)w; w += (size_t)M_ * C_ * 2;
  __bf16* wqkvb  = (__bf16*)w; w += (size_t)QKV_ * C_ * 2;
  __bf16* wprojb = (__bf16*)w; w += (size_t)C_ * C_ * 2;
  __bf16* qkv    = (__bf16*)w; w += (size_t)M_ * QKV_ * 2;
  __bf16* qn     = (__bf16*)w; w += (size_t)B_ * NH_ * T_ * HD_ * 2;
  __bf16* kn     = (__bf16*)w; w += (size_t)B_ * KVH_ * T_ * HD_ * 2;
  __bf16* vT     = (__bf16*)w; w += (size_t)B_ * KVH_ * T_ * HD_ * 2;
  __bf16* ybf    = (__bf16*)w; w += (size_t)M_ * C_ * 2;

  const int n0 = M_ * C_ / 4, n1 = QKV_ * C_ / 4, n2 = C_ * C_ / 4;
  cvt3<<<(n0 + n1 + n2 + 255) / 256, 256, 0, stream>>>(x, xb, n0, wqkv, wqkvb, n1, wproj, wprojb, n2);

  gemm_bt<__bf16><<<dim3(QKV_ / 128, M_ / 128), 256, 0, stream>>>(xb, wqkvb, qkv, QKV_, C_);
  rope_norm<<<M_ / 4, 256, 0, stream>>>(qkv, qw, kw, fc, fs, qn, kn);
  vtrans<<<dim3(T_ / 64, HD_ / 64, B_ * KVH_), 256, 0, stream>>>(qkv, vT);
  flash<<<dim3(512), 512, 0, stream>>>(qn, kn, vT, ybf);
  gemm_bt<float><<<dim3(C_ / 128, M_ / 128), 256, 0, stream>>>(ybf, wprojb, out, C_, C_);
}

// Round 6
// 322.120 us; speedup vs baseline: 1.0163x; 1.0163x over previous
//
#include <hip/hip_runtime.h>
#include <hip/hip_bf16.h>

#define B_    2
#define T_    2048
#define C_    2048
#define NH_   16
#define KVH_  4
#define HD_   128
#define QKV_  3072
#define M_    4096

typedef float  floatx4 __attribute__((ext_vector_type(4)));
typedef __bf16 bf16x8  __attribute__((ext_vector_type(8)));
typedef __bf16 bf16x4  __attribute__((ext_vector_type(4)));
typedef __bf16 bf16x2  __attribute__((ext_vector_type(2)));

typedef const __attribute__((address_space(1))) void* gas_t;
typedef __attribute__((address_space(3))) void*       las_t;
__device__ __forceinline__ void gl_lds16(const void* g, void* l) {
  __builtin_amdgcn_global_load_lds((gas_t)g, (las_t)l, 16, 0, 0);
}

// ---------------- fp32 -> bf16 conversion, all three tensors in one launch ----------
__global__ __launch_bounds__(256) void cvt3(const float* __restrict__ s0, __bf16* __restrict__ d0, int n0,
                                            const float* __restrict__ s1, __bf16* __restrict__ d1, int n1,
                                            const float* __restrict__ s2, __bf16* __restrict__ d2, int n2) {
  int i = blockIdx.x * blockDim.x + threadIdx.x;
  const float* s; __bf16* d;
  if (i < n0) { s = s0; d = d0; }
  else {
    i -= n0;
    if (i < n1) { s = s1; d = d1; }
    else { i -= n1; if (i >= n2) return; s = s2; d = d2; }
  }
  float4 f = ((const float4*)s)[i];
  bf16x4 o = { (__bf16)f.x, (__bf16)f.y, (__bf16)f.z, (__bf16)f.w };
  ((bf16x4*)d)[i] = o;
}

// ---------------- C = A[M][K] * B[N][K]^T, m97 128x128 structure (proj GEMM) ------
template <typename OutT>
__global__ __launch_bounds__(256) void gemm_bt(const __bf16* __restrict__ A,
                                               const __bf16* __restrict__ Bm,
                                               OutT* __restrict__ Cc,
                                               int N, int K) {
  __shared__ __align__(16) __bf16 As[2][128 * 32];
  __shared__ __align__(16) __bf16 Bs[2][128 * 32];
  const int tid  = threadIdx.x;
  const int wid  = tid >> 6, lane = tid & 63, quad = lane >> 4, r16 = lane & 15;
  const int bm   = blockIdx.y * 128, bn = blockIdx.x * 128;
  const int wm   = (wid >> 1) * 64, wn = (wid & 1) * 64;
  const int srow = wid * 16 + (lane >> 2);
  const int scol = (lane & 3) * 8;
  const __bf16* aptr = A  + (size_t)(bm + srow) * K + scol;
  const __bf16* bptr = Bm + (size_t)(bn + srow) * K + scol;
  const size_t rowskip = (size_t)64 * K;

  floatx4 acc[4][4];
  #pragma unroll
  for (int i = 0; i < 4; i++)
    #pragma unroll
    for (int j = 0; j < 4; j++) acc[i][j] = (floatx4){0.f, 0.f, 0.f, 0.f};

  for (int k0 = 0; k0 < K; k0 += 64) {
    #pragma unroll
    for (int hf = 0; hf < 2; hf++) {
      gl_lds16(aptr + k0 + hf * 32,           &As[hf][wid * 512]);
      gl_lds16(aptr + rowskip + k0 + hf * 32, &As[hf][2048 + wid * 512]);
      gl_lds16(bptr + k0 + hf * 32,           &Bs[hf][wid * 512]);
      gl_lds16(bptr + rowskip + k0 + hf * 32, &Bs[hf][2048 + wid * 512]);
    }
    __syncthreads();

    #pragma unroll
    for (int hf = 0; hf < 2; hf++) {
      bf16x8 af[4], bfr[4];
      #pragma unroll
      for (int i = 0; i < 4; i++) af[i]  = *(const bf16x8*)&As[hf][(wm + i * 16 + r16) * 32 + quad * 8];
      #pragma unroll
      for (int j = 0; j < 4; j++) bfr[j] = *(const bf16x8*)&Bs[hf][(wn + j * 16 + r16) * 32 + quad * 8];
      #pragma unroll
      for (int i = 0; i < 4; i++)
        #pragma unroll
        for (int j = 0; j < 4; j++)
          acc[i][j] = __builtin_amdgcn_mfma_f32_16x16x32_bf16(af[i], bfr[j], acc[i][j], 0, 0, 0);
    }
    __syncthreads();
  }

  #pragma unroll
  for (int i = 0; i < 4; i++) {
    #pragma unroll
    for (int reg = 0; reg < 4; reg++) {
      int row = bm + wm + i * 16 + quad * 4 + reg;
      OutT* crow = Cc + (size_t)row * N + bn + wn;
      #pragma unroll
      for (int j = 0; j < 4; j++) crow[j * 16 + r16] = (OutT)acc[i][j][reg];
    }
  }
}

// ---------------- 256x256 counted-vmcnt GEMM (QKV): C = A[M][K] * B[N][K]^T ------
// T3/T4 schedule with a provable ledger: LDS = ring of 10 half-tile slots (16KB
// each, 160KB total, 1 block/CU).  Half-stream h: tile j=h>>2, part q=h&3
// (A rows 0-127 / A 128-255 / B 0-127 / B 128-255).  During tile j's 4 phases we
// issue halves 4j+6..4j+9 (their slots held tile j-1's halves, sealed by the
// boundary barrier).  At tile-j start the issued frontier is 4j+5; needing half
// 4j+3 complete => uniform s_waitcnt vmcnt(4) (2 loads/half) -- loads stay in
// flight across barriers; vmcnt(0) only before the last tile.  Each wave waits
// on its OWN loads then barriers; all waves stage the same positions, so the
// barrier makes all halves <=4j+3 collectively complete.
// LDS layout per half: [lrhi(8)][cc(8)][slot16], slot = (lr&15)^cc -- the
// chunk-XOR family that measured EXACTLY 0 bank conflicts in flash r5.  Staged
// via linear global_load_lds dest + pre-swizzled per-lane global source
// (both-sides rule); fragment reads apply the same XOR.
// 8 waves 2x4; per-wave output 128x64 (acc[8][4]); 16 MFMAs per phase under
// setprio (one 64x32 C-quadrant x K=64).
template <typename OutT>
__global__ __launch_bounds__(512, 2) void gemm256(const __bf16* __restrict__ A,
                                                  const __bf16* __restrict__ Bm,
                                                  OutT* __restrict__ Cc,
                                                  int N, int K) {
  __shared__ __align__(16) __bf16 ring[10 * 8192];   // 160 KiB
  const int tid  = threadIdx.x;
  const int lane = tid & 63, quad = lane >> 4, r16 = lane & 15;
  const int wid  = tid >> 6;
  const int wm   = wid >> 2, wn = wid & 3;
  const int bm   = blockIdx.y * 256, bn = blockIdx.x * 256;
  const int nt   = K >> 6;
  const int wbase = tid & ~63;
  const int lb   = (wn & 1) * 4;          // B local lrhi base

  floatx4 acc[8][4];
  #pragma unroll
  for (int i = 0; i < 8; i++)
    #pragma unroll
    for (int j = 0; j < 4; j++) acc[i][j] = (floatx4){0.f, 0.f, 0.f, 0.f};

  // stage one half-tile h into ring slot `slot` (2 x global_load_lds / thread)
  auto stage = [&](int h, int slot) {
    const int kt = h >> 2, q = h & 3;
    const __bf16* gb = (q < 2) ? (A  + (size_t)(bm + (q << 7)) * K)
                               : (Bm + (size_t)(bn + ((q - 2) << 7)) * K);
    #pragma unroll
    for (int is = 0; is < 2; is++) {
      const int s   = is * 512 + tid;
      const int lrh = s >> 7, cc = (s >> 4) & 7, sl = s & 15;
      const int lr  = lrh * 16 + (sl ^ cc);              // pre-swizzled source row
      gl_lds16(gb + (size_t)lr * K + (kt << 6) + (cc << 3),
               &ring[slot * 8192 + (is * 512 + wbase) * 8]);  // linear dest
    }
  };

  // prologue: issue halves 0..5 (tiles 0 + A-halves of tile 1)
  #pragma unroll 1
  for (int h = 0; h < 6; ++h)
    if (h < 4 * nt) stage(h, h);

  #pragma unroll 1
  for (int j = 0; j < nt; ++j) {
    // ---- tile boundary: counted wait + barrier (+compiler fence) ----
    if (j + 1 < nt) { asm volatile("s_waitcnt vmcnt(4)" ::: "memory"); }
    else            { asm volatile("s_waitcnt vmcnt(0)" ::: "memory"); }
    __builtin_amdgcn_s_barrier();
    asm volatile("" ::: "memory");     // no LDS read / gload issue may hoist above

    const int b4 = (4 * j) % 10;
    const __bf16* Ah = &ring[((b4 + wm) % 10) * 8192];
    const __bf16* Bh = &ring[((b4 + 2 + (wn >> 1)) % 10) * 8192];
    const int h0 = 4 * j + 6, hend = 4 * nt;

    bf16x8 af[4][2], bfr[2][2];

    // ---- phase 0: quadrant (mh=0, nh=0) ----
    #pragma unroll
    for (int i = 0; i < 4; i++)
      #pragma unroll
      for (int ks = 0; ks < 2; ks++) {
        const int cc = ks * 4 + quad;
        af[i][ks] = *(const bf16x8*)&Ah[i * 1024 + cc * 128 + ((r16 ^ cc) << 3)];
      }
    #pragma unroll
    for (int i = 0; i < 2; i++)
      #pragma unroll
      for (int ks = 0; ks < 2; ks++) {
        const int cc = ks * 4 + quad;
        bfr[i][ks] = *(const bf16x8*)&Bh[(lb + i) * 1024 + cc * 128 + ((r16 ^ cc) << 3)];
      }
    if (h0 < hend) stage(h0, (b4 + 6) % 10);
    __builtin_amdgcn_s_barrier();
    __builtin_amdgcn_s_setprio(1);
    #pragma unroll
    for (int ks = 0; ks < 2; ks++)
      #pragma unroll
      for (int i = 0; i < 4; i++)
        #pragma unroll
        for (int jj = 0; jj < 2; jj++)
          acc[i][jj] = __builtin_amdgcn_mfma_f32_16x16x32_bf16(af[i][ks], bfr[jj][ks], acc[i][jj], 0, 0, 0);
    __builtin_amdgcn_s_setprio(0);
    __builtin_amdgcn_s_barrier();

    // ---- phase 1: quadrant (mh=0, nh=1) ----
    #pragma unroll
    for (int i = 0; i < 2; i++)
      #pragma unroll
      for (int ks = 0; ks < 2; ks++) {
        const int cc = ks * 4 + quad;
        bfr[i][ks] = *(const bf16x8*)&Bh[(lb + 2 + i) * 1024 + cc * 128 + ((r16 ^ cc) << 3)];
      }
    if (h0 + 1 < hend) stage(h0 + 1, (b4 + 7) % 10);
    __builtin_amdgcn_s_barrier();
    __builtin_amdgcn_s_setprio(1);
    #pragma unroll
    for (int ks = 0; ks < 2; ks++)
      #pragma unroll
      for (int i = 0; i < 4; i++)
        #pragma unroll
        for (int jj = 0; jj < 2; jj++)
          acc[i][2 + jj] = __builtin_amdgcn_mfma_f32_16x16x32_bf16(af[i][ks], bfr[jj][ks], acc[i][2 + jj], 0, 0, 0);
    __builtin_amdgcn_s_setprio(0);
    __builtin_amdgcn_s_barrier();

    // ---- phase 2: quadrant (mh=1, nh=0) ----
    #pragma unroll
    for (int i = 0; i < 4; i++)
      #pragma unroll
      for (int ks = 0; ks < 2; ks++) {
        const int cc = ks * 4 + quad;
        af[i][ks] = *(const bf16x8*)&Ah[(4 + i) * 1024 + cc * 128 + ((r16 ^ cc) << 3)];
      }
    #pragma unroll
    for (int i = 0; i < 2; i++)
      #pragma unroll
      for (int ks = 0; ks < 2; ks++) {
        const int cc = ks * 4 + quad;
        bfr[i][ks] = *(const bf16x8*)&Bh[(lb + i) * 1024 + cc * 128 + ((r16 ^ cc) << 3)];
      }
    if (h0 + 2 < hend) stage(h0 + 2, (b4 + 8) % 10);
    __builtin_amdgcn_s_barrier();
    __builtin_amdgcn_s_setprio(1);
    #pragma unroll
    for (int ks = 0; ks < 2; ks++)
      #pragma unroll
      for (int i = 0; i < 4; i++)
        #pragma unroll
        for (int jj = 0; jj < 2; jj++)
          acc[4 + i][jj] = __builtin_amdgcn_mfma_f32_16x16x32_bf16(af[i][ks], bfr[jj][ks], acc[4 + i][jj], 0, 0, 0);
    __builtin_amdgcn_s_setprio(0);
    __builtin_amdgcn_s_barrier();

    // ---- phase 3: quadrant (mh=1, nh=1) ----
    #pragma unroll
    for (int i = 0; i < 2; i++)
      #pragma unroll
      for (int ks = 0; ks < 2; ks++) {
        const int cc = ks * 4 + quad;
        bfr[i][ks] = *(const bf16x8*)&Bh[(lb + 2 + i) * 1024 + cc * 128 + ((r16 ^ cc) << 3)];
      }
    if (h0 + 3 < hend) stage(h0 + 3, (b4 + 9) % 10);
    __builtin_amdgcn_s_barrier();
    __builtin_amdgcn_s_setprio(1);
    #pragma unroll
    for (int ks = 0; ks < 2; ks++)
      #pragma unroll
      for (int i = 0; i < 4; i++)
        #pragma unroll
        for (int jj = 0; jj < 2; jj++)
          acc[4 + i][2 + jj] = __builtin_amdgcn_mfma_f32_16x16x32_bf16(af[i][ks], bfr[jj][ks], acc[4 + i][2 + jj], 0, 0, 0);
    __builtin_amdgcn_s_setprio(0);
    __builtin_amdgcn_s_barrier();
  }

  #pragma unroll
  for (int mi = 0; mi < 8; mi++)
    #pragma unroll
    for (int reg = 0; reg < 4; reg++) {
      const int row = bm + wm * 128 + mi * 16 + quad * 4 + reg;
      OutT* crow = Cc + (size_t)row * N + bn + wn * 64;
      #pragma unroll
      for (int ni = 0; ni < 4; ni++) crow[ni * 16 + r16] = (OutT)acc[mi][ni][reg];
    }
}

// ---------------- RoPE + RMSNorm (bf16 qkv input), one wave per (b,t) row ----------
__global__ __launch_bounds__(256) void rope_norm(const __bf16* __restrict__ qkv,
                                                 const float* __restrict__ qw,
                                                 const float* __restrict__ kw,
                                                 const float* __restrict__ fc,
                                                 const float* __restrict__ fs,
                                                 __bf16* __restrict__ qn,
                                                 __bf16* __restrict__ kn) {
  const int tid  = threadIdx.x;
  const int wid  = tid >> 6, lane = tid & 63;
  const int row  = blockIdx.x * 4 + wid;        // b*T + t
  const int b    = row >> 11, t = row & (T_ - 1);
  const float cs = fc[t * 64 + lane], sn = fs[t * 64 + lane];
  const __bf16* base = qkv + (size_t)row * QKV_;

  #pragma unroll 2
  for (int h = 0; h < NH_; h++) {
    bf16x2 ab = *(const bf16x2*)(base + h * HD_ + 2 * lane);
    float ax = (float)ab[0], ay = (float)ab[1];
    float oa = ax * cs - ay * sn;
    float ob = ax * sn + ay * cs;
    float ss = oa * oa + ob * ob;
    #pragma unroll
    for (int off = 32; off; off >>= 1) ss += __shfl_xor(ss, off);
    float rinv = rsqrtf(ss * (1.0f / HD_) + 1e-6f);
    bf16x2 o = { (__bf16)(oa * rinv * qw[2 * lane]), (__bf16)(ob * rinv * qw[2 * lane + 1]) };
    *(bf16x2*)&qn[(size_t)((b * NH_ + h) * T_ + t) * HD_ + 2 * lane] = o;
  }
  #pragma unroll 2
  for (int h = 0; h < KVH_; h++) {
    bf16x2 ab = *(const bf16x2*)(base + C_ + h * HD_ + 2 * lane);
    float ax = (float)ab[0], ay = (float)ab[1];
    float oa = ax * cs - ay * sn;
    float ob = ax * sn + ay * cs;
    float ss = oa * oa + ob * ob;
    #pragma unroll
    for (int off = 32; off; off >>= 1) ss += __shfl_xor(ss, off);
    float rinv = rsqrtf(ss * (1.0f / HD_) + 1e-6f);
    bf16x2 o = { (__bf16)(oa * rinv * kw[2 * lane]), (__bf16)(ob * rinv * kw[2 * lane + 1]) };
    *(bf16x2*)&kn[(size_t)((b * KVH_ + h) * T_ + t) * HD_ + 2 * lane] = o;
  }
}

// ---------------- V transpose: qkv bf16 [t][d] -> vT bf16 [d][t], 64x64 LDS tiles ----
__global__ __launch_bounds__(256) void vtrans(const __bf16* __restrict__ qkv,
                                              __bf16* __restrict__ vT) {
  __shared__ __bf16 L[64 * 68];
  const int tid = threadIdx.x;
  const int t0 = blockIdx.x * 64;
  const int d0 = blockIdx.y * 64;
  const int z  = blockIdx.z;            // b*KVH + hk
  const int b  = z >> 2, hk = z & 3;
  const int srcc = C_ + KVH_ * HD_ + hk * HD_ + d0;
  const int rr = tid >> 4, c4 = (tid & 15) * 4;
  #pragma unroll
  for (int i = 0; i < 4; i++) {
    int t = rr + i * 16;
    bf16x4 f = *(const bf16x4*)&qkv[(size_t)(b * T_ + t0 + t) * QKV_ + srcc + c4];
    *(bf16x4*)&L[t * 68 + c4] = f;
  }
  __syncthreads();
  const int dr = tid >> 3, tc8 = (tid & 7) * 8;
  #pragma unroll
  for (int i = 0; i < 2; i++) {
    int d = dr + i * 32;
    bf16x8 ov;
    #pragma unroll
    for (int j = 0; j < 8; j++) ov[j] = L[(tc8 + j) * 68 + d];
    *(bf16x8*)&vT[(size_t)(z * HD_ + d0 + d) * T_ + t0 + tc8] = ov;
  }
}

// ---------------- causal flash attention: 512 threads, 8 waves x 16 rows ----------
// r6 = exact r4 revert (best measured flash: 83.3us).  r5's full-width P hit
// exactly-80KB LDS and lost the 2nd block/CU (-12%) despite 0 bank conflicts.
// Keeps: dbuf Ks/Vs + single barrier per K-tile, chunk-swizzled K/V layout,
// chunked P [16][48], setprio, defer-max.  Grid = 512 (2 blocks/CU): x<256
// takes heavy tile qt=15-p, x+256 the light tile qt=p.
__device__ __forceinline__ int swz_w(int lane) {       // write slot for chunk (kt=lane>>2, ds=lane&3)
  return ((lane & 3) << 4) | ((lane >> 2) ^ ((lane & 3) << 1));
}
__device__ __forceinline__ int swz_r(int quad, int r16) { // read slot for (kt=r16, ds=quad)
  return (quad << 4) | (r16 ^ (quad << 1));
}

__device__ __forceinline__ void kv_prefetch8(const __bf16* kbase, const __bf16* vbase,
                                             int kt0, int wid, int lane,
                                             bf16x8 kreg[2], bf16x8 vreg[2]) {
  const int r4 = lane >> 2, c8 = (lane & 3) * 8;
  #pragma unroll
  for (int i = 0; i < 2; i++) {
    const int n = wid * 2 + i;   // K tile: kt4 = n>>2 (16 kt rows), d4 = n&3 (32 d cols)
    kreg[i] = *(const bf16x8*)&kbase[(size_t)(kt0 + (n >> 2) * 16 + r4) * HD_ + (n & 3) * 32 + c8];
    vreg[i] = *(const bf16x8*)&vbase[(size_t)((n >> 1) * 16 + r4) * T_ + kt0 + (n & 1) * 32 + c8];
  }
}

__device__ __forceinline__ void kv_commit8(__bf16* Ks, __bf16* Vs, int wid, int lane,
                                           const bf16x8 kreg[2], const bf16x8 vreg[2]) {
  const int slot = swz_w(lane);
  #pragma unroll
  for (int i = 0; i < 2; i++) {
    *(bf16x8*)(Ks + (wid * 2 + i) * 512 + slot * 8) = kreg[i];
    *(bf16x8*)(Vs + (wid * 2 + i) * 512 + slot * 8) = vreg[i];
  }
}

__global__ __launch_bounds__(512, 4) void flash(const __bf16* __restrict__ q,
                                                const __bf16* __restrict__ k,
                                                const __bf16* __restrict__ vT,
                                                __bf16* __restrict__ y) {
  __shared__ __align__(16) __bf16 Ks[2][64 * 128];  // dbuf x 16 swizzled tiles [16kt][32d]
  __shared__ __align__(16) __bf16 Vs[2][64 * 128];  // dbuf x 16 swizzled tiles [16d][32kt]
  __shared__ __align__(16) __bf16 Ps[8][16 * 48];   // per-wave P chunk scratch (32 cols)
  const int tid = threadIdx.x;
  const int wid = tid >> 6, lane = tid & 63, quad = lane >> 4, r16 = lane & 15;
  const int x   = blockIdx.x;
  const int p   = (x >> 5) & 7, hl = x & 31;
  const int qt  = (x < 256) ? (15 - p) : p;       // heavy half first; x and x+256 pair on one CU
  const int b = hl >> 4, h = hl & 15, hk = h >> 2;

  const __bf16* kbase = k  + (size_t)(b * KVH_ + hk) * T_ * HD_;
  const __bf16* vbase = vT + (size_t)(b * KVH_ + hk) * HD_ * T_;
  __bf16* Pw = Ps[wid];
  const float sc = 0.08838834764831845f;  // 1/sqrt(128)
  const float NEG = -__builtin_inff();
  bf16x8 ones;
  #pragma unroll
  for (int i = 0; i < 8; i++) ones[i] = (__bf16)1.0f;

  const int nt = 2 * (qt + 1);
  const int r0 = qt * 128 + wid * 16;   // this wave's 16 q-rows

  const __bf16* qrow = q + ((size_t)(b * NH_ + h) * T_ + r0 + r16) * HD_;
  bf16x8 qf[4];
  #pragma unroll
  for (int kb = 0; kb < 4; kb++) qf[kb] = *(const bf16x8*)&qrow[kb * 32 + quad * 8];

  floatx4 o[8], ol = (floatx4){0.f, 0.f, 0.f, 0.f};
  #pragma unroll
  for (int j = 0; j < 8; j++) o[j] = (floatx4){0.f, 0.f, 0.f, 0.f};
  float m_r[4] = {NEG, NEG, NEG, NEG};

  bf16x8 kreg[2], vreg[2];
  kv_prefetch8(kbase, vbase, 0, wid, lane, kreg, vreg);
  kv_commit8(&Ks[0][0], &Vs[0][0], wid, lane, kreg, vreg);
  if (nt > 1) kv_prefetch8(kbase, vbase, 64, wid, lane, kreg, vreg);
  __syncthreads();                        // tile 0 visible

  #pragma unroll 1
  for (int it = 0; it < nt; ++it) {
    if (it + 1 < nt) {
      // buf[(it+1)&1]'s previous readers (tile it-1) finished at the barrier
      // ending iter it-1, so this commit is race-free.
      kv_commit8(&Ks[(it + 1) & 1][0], &Vs[(it + 1) & 1][0], wid, lane, kreg, vreg);
      if (it + 2 < nt) kv_prefetch8(kbase, vbase, (it + 2) * 64, wid, lane, kreg, vreg);
    }

    const int kt0 = it * 64;
    const __bf16* Kb = &Ks[it & 1][0];
    const __bf16* Vb = &Vs[it & 1][0];
    if (kt0 <= r0 + 15) {                 // wave-uniform causal skip (no barriers inside)
      floatx4 s[4];
      #pragma unroll
      for (int cb = 0; cb < 4; cb++) s[cb] = (floatx4){0.f, 0.f, 0.f, 0.f};
      __builtin_amdgcn_s_setprio(1);
      #pragma unroll
      for (int kb = 0; kb < 4; kb++)
        #pragma unroll
        for (int cb = 0; cb < 4; cb++) {
          bf16x8 kf = *(const bf16x8*)&Kb[(cb * 4 + kb) * 512 + swz_r(quad, r16) * 8];
          s[cb] = __builtin_amdgcn_mfma_f32_16x16x32_bf16(qf[kb], kf, s[cb], 0, 0, 0);
        }
      __builtin_amdgcn_s_setprio(0);

      // scale + causal mask in place
      const bool needmask = (kt0 + 63 > r0);  // wave-uniform
      #pragma unroll
      for (int reg = 0; reg < 4; reg++) {
        const int rowq = r0 + quad * 4 + reg;
        s[0][reg] *= sc; s[1][reg] *= sc; s[2][reg] *= sc; s[3][reg] *= sc;
        if (needmask) {
          if (kt0 +      r16 > rowq) s[0][reg] = NEG;
          if (kt0 + 16 + r16 > rowq) s[1][reg] = NEG;
          if (kt0 + 32 + r16 > rowq) s[2][reg] = NEG;
          if (kt0 + 48 + r16 > rowq) s[3][reg] = NEG;
        }
      }
      // per-row max + running-max bookkeeping
      float mx[4], mnew[4];
      #pragma unroll
      for (int reg = 0; reg < 4; reg++) {
        float m0 = fmaxf(fmaxf(s[0][reg], s[1][reg]), fmaxf(s[2][reg], s[3][reg]));
        #pragma unroll
        for (int off = 8; off; off >>= 1) m0 = fmaxf(m0, __shfl_xor(m0, off));
        mx[reg] = m0;
        mnew[reg] = fmaxf(m_r[reg], m0);
      }
      // T13 defer-max: if no row grew its max by >8, keep old m (P bounded by e^8)
      float growth = fmaxf(fmaxf(mx[0] - m_r[0], mx[1] - m_r[1]),
                           fmaxf(mx[2] - m_r[2], mx[3] - m_r[3]));
      if (!__all(growth <= 8.0f)) {
        #pragma unroll
        for (int reg = 0; reg < 4; reg++) {
          float a = __expf(m_r[reg] - mnew[reg]);
          m_r[reg] = mnew[reg];
          ol[reg] *= a;
          #pragma unroll
          for (int j = 0; j < 8; j++) o[j][reg] *= a;
        }
      }
      // two 32-col chunks: exp -> Pw -> P-frag -> rowsum + PV MFMAs
      #pragma unroll
      for (int c = 0; c < 2; c++) {
        #pragma unroll
        for (int reg = 0; reg < 4; reg++) {
          const int prow = quad * 4 + reg;
          Pw[prow * 48 +      r16] = (__bf16)__expf(s[2 * c    ][reg] - m_r[reg]);
          Pw[prow * 48 + 16 + r16] = (__bf16)__expf(s[2 * c + 1][reg] - m_r[reg]);
        }
        __asm__ volatile("" ::: "memory");  // wave-private P: writes before reads
        bf16x8 pf = *(const bf16x8*)&Pw[r16 * 48 + quad * 8];
        __builtin_amdgcn_s_setprio(1);
        ol = __builtin_amdgcn_mfma_f32_16x16x32_bf16(pf, ones, ol, 0, 0, 0);
        #pragma unroll
        for (int j = 0; j < 8; j++) {
          bf16x8 vf = *(const bf16x8*)&Vb[(j * 2 + c) * 512 + swz_r(quad, r16) * 8];
          o[j] = __builtin_amdgcn_mfma_f32_16x16x32_bf16(pf, vf, o[j], 0, 0, 0);
        }
        __builtin_amdgcn_s_setprio(0);
        __asm__ volatile("" ::: "memory");  // keep chunk1 writes after chunk0 reads
      }
    }
    __syncthreads();                      // seals tile it reads; publishes tile it+1
  }

  #pragma unroll
  for (int reg = 0; reg < 4; reg++) {
    int trow = r0 + quad * 4 + reg;
    float inv = 1.0f / ol[reg];  // rowsum identical across lanes (ones-MFMA trick)
    __bf16* yr = y + ((size_t)(b * T_) + trow) * C_ + h * HD_;
    #pragma unroll
    for (int j = 0; j < 8; j++) yr[j * 16 + r16] = (__bf16)(o[j][reg] * inv);
  }
}

extern "C" void kernel_launch(void* const* d_in, const int* in_sizes, int n_in,
                              void* d_out, int out_size, void* d_ws, size_t ws_size,
                              hipStream_t stream) {
  const float* x     = (const float*)d_in[0];
  const float* wqkv  = (const float*)d_in[1];
  const float* wproj = (const float*)d_in[2];
  const float* qw    = (const float*)d_in[3];
  const float* kw    = (const float*)d_in[4];
  const float* fc    = (const float*)d_in[5];
  const float* fs    = (const float*)d_in[6];
  float* out = (float*)d_out;

  char* w = (char*)d_ws;
  __bf16* xb     = (__bf16*)w; w += (size_t)M_ * C_ * 2;
  __bf16* wqkvb  = (__bf16*)w; w += (size_t)QKV_ * C_ * 2;
  __bf16* wprojb = (__bf16*)w; w += (size_t)C_ * C_ * 2;
  __bf16* qkv    = (__bf16*)w; w += (size_t)M_ * QKV_ * 2;
  __bf16* qn     = (__bf16*)w; w += (size_t)B_ * NH_ * T_ * HD_ * 2;
  __bf16* kn     = (__bf16*)w; w += (size_t)B_ * KVH_ * T_ * HD_ * 2;
  __bf16* vT     = (__bf16*)w; w += (size_t)B_ * KVH_ * T_ * HD_ * 2;
  __bf16* ybf    = (__bf16*)w; w += (size_t)M_ * C_ * 2;

  const int n0 = M_ * C_ / 4, n1 = QKV_ * C_ / 4, n2 = C_ * C_ / 4;
  cvt3<<<(n0 + n1 + n2 + 255) / 256, 256, 0, stream>>>(x, xb, n0, wqkv, wqkvb, n1, wproj, wprojb, n2);

  gemm256<__bf16><<<dim3(QKV_ / 256, M_ / 256), 512, 0, stream>>>(xb, wqkvb, qkv, QKV_, C_);
  rope_norm<<<M_ / 4, 256, 0, stream>>>(qkv, qw, kw, fc, fs, qn, kn);
  vtrans<<<dim3(T_ / 64, HD_ / 64, B_ * KVH_), 256, 0, stream>>>(qkv, vT);
  flash<<<dim3(512), 512, 0, stream>>>(qn, kn, vT, ybf);
  gemm_bt<float><<<dim3(C_ / 128, M_ / 128), 256, 0, stream>>>(ybf, wprojb, out, C_, C_);
}

// Round 7
// 315.989 us; speedup vs baseline: 1.0360x; 1.0194x over previous
//
#include <hip/hip_runtime.h>
#include <hip/hip_bf16.h>

#define B_    2
#define T_    2048
#define C_    2048
#define NH_   16
#define KVH_  4
#define HD_   128
#define QKV_  3072
#define M_    4096

typedef float  floatx4 __attribute__((ext_vector_type(4)));
typedef __bf16 bf16x8  __attribute__((ext_vector_type(8)));
typedef __bf16 bf16x4  __attribute__((ext_vector_type(4)));
typedef __bf16 bf16x2  __attribute__((ext_vector_type(2)));

typedef const __attribute__((address_space(1))) void* gas_t;
typedef __attribute__((address_space(3))) void*       las_t;
__device__ __forceinline__ void gl_lds16(const void* g, void* l) {
  __builtin_amdgcn_global_load_lds((gas_t)g, (las_t)l, 16, 0, 0);
}

// ---------------- fp32 -> bf16 conversion, all three tensors in one launch ----------
__global__ __launch_bounds__(256) void cvt3(const float* __restrict__ s0, __bf16* __restrict__ d0, int n0,
                                            const float* __restrict__ s1, __bf16* __restrict__ d1, int n1,
                                            const float* __restrict__ s2, __bf16* __restrict__ d2, int n2) {
  int i = blockIdx.x * blockDim.x + threadIdx.x;
  const float* s; __bf16* d;
  if (i < n0) { s = s0; d = d0; }
  else {
    i -= n0;
    if (i < n1) { s = s1; d = d1; }
    else { i -= n1; if (i >= n2) return; s = s2; d = d2; }
  }
  float4 f = ((const float4*)s)[i];
  bf16x4 o = { (__bf16)f.x, (__bf16)f.y, (__bf16)f.z, (__bf16)f.w };
  ((bf16x4*)d)[i] = o;
}

// ---------------- counted-vmcnt 128x128 GEMM: C = A[M][K] * B[N][K]^T --------------
// T3/T4 minimum-2-phase pipeline on the m97 tile (full CU fill: QKV 768 blocks,
// proj 512; 64KB LDS -> 2 blocks/CU).  Per K-tile j: issue tile j+1's 8
// global_load_lds FIRST, then s_waitcnt vmcnt(8) (tile j's own loads complete;
// j+1's stay in flight ACROSS both barriers -- never vmcnt(0) in the main loop),
// raw s_barrier, 32 MFMAs under setprio, s_barrier.  Ledger: stage(j+1) targets
// buf[(j+1)&1] whose readers (tile j-1) were sealed by the end-of-(j-1) barrier.
// Raw barriers + asm memory fences both sides (cannot use __syncthreads -- the
// compiler re-inserts the vmcnt(0) drain it emits before s_barrier).
// LDS layout [128][64] with chunk-XOR swizzle: 16B chunk c of row r stored at
// phys slot c ^ (r&7).  Read phase (16 lanes, fixed quad): slots (hf*4+quad) ^
// (r16&7) -> 8 distinct 16B slots x 2 lanes = 2/bank, free.  Staging keeps the
// gl_lds dest LINEAR (wave-uniform base, lane x 16B) and pre-swizzles the per-
// lane GLOBAL source column (both-sides rule): lane covers row wid*8+(l>>3),
// phys chunk l&7, source k-chunk (l&7)^(srow&7).
template <typename OutT>
__global__ __launch_bounds__(256, 2) void gemm_cnt(const __bf16* __restrict__ A,
                                                   const __bf16* __restrict__ Bm,
                                                   OutT* __restrict__ Cc,
                                                   int N, int K) {
  __shared__ __align__(16) __bf16 As[2][128 * 64];
  __shared__ __align__(16) __bf16 Bs[2][128 * 64];
  const int tid  = threadIdx.x;
  const int wid  = tid >> 6, lane = tid & 63, quad = lane >> 4, r16 = lane & 15;
  const int bm   = blockIdx.y * 128, bn = blockIdx.x * 128;
  const int wm   = (wid >> 1) * 64, wn = (wid & 1) * 64;
  const int srow = tid >> 3;                       // 0..31 (row within 32-row pass)
  const int clog = (tid & 7) ^ (srow & 7);         // pre-swizzled source k-chunk
  const __bf16* aR = A  + (size_t)(bm + srow) * K + clog * 8;
  const __bf16* bR = Bm + (size_t)(bn + srow) * K + clog * 8;
  const int nt = K >> 6;

  floatx4 acc[4][4];
  #pragma unroll
  for (int i = 0; i < 4; i++)
    #pragma unroll
    for (int j = 0; j < 4; j++) acc[i][j] = (floatx4){0.f, 0.f, 0.f, 0.f};

  auto stage = [&](int s, int k0) {   // 8 gl_lds16 / thread (4 A + 4 B)
    #pragma unroll
    for (int p = 0; p < 4; p++) {
      gl_lds16(aR + (size_t)(p * 32) * K + k0, &As[s][(p * 32 + wid * 8) * 64]);
      gl_lds16(bR + (size_t)(p * 32) * K + k0, &Bs[s][(p * 32 + wid * 8) * 64]);
    }
  };

  stage(0, 0);                                     // prologue: tile 0 in flight

  #pragma unroll 1
  for (int j = 0; j < nt; ++j) {
    if (j + 1 < nt) {
      stage((j + 1) & 1, (j + 1) << 6);            // issue next tile (8 loads)
      asm volatile("s_waitcnt vmcnt(8)" ::: "memory");  // tile j done, j+1 flying
    } else {
      asm volatile("s_waitcnt vmcnt(0)" ::: "memory");  // last tile: drain
    }
    __builtin_amdgcn_s_barrier();                  // all waves' tile-j loads visible
    asm volatile("" ::: "memory");

    const __bf16* Ab = As[j & 1];
    const __bf16* Bb = Bs[j & 1];
    #pragma unroll
    for (int hf = 0; hf < 2; hf++) {
      const int xo = (((hf << 2) + quad) ^ (r16 & 7)) << 3;  // swizzled chunk offset
      bf16x8 af[4], bfr[4];
      #pragma unroll
      for (int i = 0; i < 4; i++) af[i]  = *(const bf16x8*)&Ab[(wm + i * 16 + r16) * 64 + xo];
      #pragma unroll
      for (int i = 0; i < 4; i++) bfr[i] = *(const bf16x8*)&Bb[(wn + i * 16 + r16) * 64 + xo];
      __builtin_amdgcn_s_setprio(1);
      #pragma unroll
      for (int i = 0; i < 4; i++)
        #pragma unroll
        for (int jj = 0; jj < 4; jj++)
          acc[i][jj] = __builtin_amdgcn_mfma_f32_16x16x32_bf16(af[i], bfr[jj], acc[i][jj], 0, 0, 0);
      __builtin_amdgcn_s_setprio(0);
    }
    asm volatile("" ::: "memory");
    __builtin_amdgcn_s_barrier();                  // seal buf[j&1] reads (reused at j+2)
    asm volatile("" ::: "memory");
  }

  #pragma unroll
  for (int i = 0; i < 4; i++) {
    #pragma unroll
    for (int reg = 0; reg < 4; reg++) {
      int row = bm + wm + i * 16 + quad * 4 + reg;
      OutT* crow = Cc + (size_t)row * N + bn + wn;
      #pragma unroll
      for (int j = 0; j < 4; j++) crow[j * 16 + r16] = (OutT)acc[i][j][reg];
    }
  }
}

// ---------------- fused RoPE+RMSNorm (blocks 0..1023) + V transpose (1024..1535) ----
__global__ __launch_bounds__(256) void ropevt(const __bf16* __restrict__ qkv,
                                              const float* __restrict__ qw,
                                              const float* __restrict__ kw,
                                              const float* __restrict__ fc,
                                              const float* __restrict__ fs,
                                              __bf16* __restrict__ qn,
                                              __bf16* __restrict__ kn,
                                              __bf16* __restrict__ vT) {
  __shared__ __bf16 L[64 * 68];
  const int tid = threadIdx.x;
  if (blockIdx.x < M_ / 4) {
    // ---- rope_norm body (unchanged) ----
    const int wid  = tid >> 6, lane = tid & 63;
    const int row  = blockIdx.x * 4 + wid;        // b*T + t
    const int b    = row >> 11, t = row & (T_ - 1);
    const float cs = fc[t * 64 + lane], sn = fs[t * 64 + lane];
    const __bf16* base = qkv + (size_t)row * QKV_;

    #pragma unroll 2
    for (int h = 0; h < NH_; h++) {
      bf16x2 ab = *(const bf16x2*)(base + h * HD_ + 2 * lane);
      float ax = (float)ab[0], ay = (float)ab[1];
      float oa = ax * cs - ay * sn;
      float ob = ax * sn + ay * cs;
      float ss = oa * oa + ob * ob;
      #pragma unroll
      for (int off = 32; off; off >>= 1) ss += __shfl_xor(ss, off);
      float rinv = rsqrtf(ss * (1.0f / HD_) + 1e-6f);
      bf16x2 o = { (__bf16)(oa * rinv * qw[2 * lane]), (__bf16)(ob * rinv * qw[2 * lane + 1]) };
      *(bf16x2*)&qn[(size_t)((b * NH_ + h) * T_ + t) * HD_ + 2 * lane] = o;
    }
    #pragma unroll 2
    for (int h = 0; h < KVH_; h++) {
      bf16x2 ab = *(const bf16x2*)(base + C_ + h * HD_ + 2 * lane);
      float ax = (float)ab[0], ay = (float)ab[1];
      float oa = ax * cs - ay * sn;
      float ob = ax * sn + ay * cs;
      float ss = oa * oa + ob * ob;
      #pragma unroll
      for (int off = 32; off; off >>= 1) ss += __shfl_xor(ss, off);
      float rinv = rsqrtf(ss * (1.0f / HD_) + 1e-6f);
      bf16x2 o = { (__bf16)(oa * rinv * kw[2 * lane]), (__bf16)(ob * rinv * kw[2 * lane + 1]) };
      *(bf16x2*)&kn[(size_t)((b * KVH_ + h) * T_ + t) * HD_ + 2 * lane] = o;
    }
    return;
  }
  // ---- vtrans body (unchanged; grid (32,2,8) flattened) ----
  const int idx = blockIdx.x - M_ / 4;
  const int t0 = (idx & 31) * 64;
  const int d0 = ((idx >> 5) & 1) * 64;
  const int z  = idx >> 6;              // b*KVH + hk
  const int b  = z >> 2, hk = z & 3;
  const int srcc = C_ + KVH_ * HD_ + hk * HD_ + d0;
  const int rr = tid >> 4, c4 = (tid & 15) * 4;
  #pragma unroll
  for (int i = 0; i < 4; i++) {
    int t = rr + i * 16;
    bf16x4 f = *(const bf16x4*)&qkv[(size_t)(b * T_ + t0 + t) * QKV_ + srcc + c4];
    *(bf16x4*)&L[t * 68 + c4] = f;
  }
  __syncthreads();
  const int dr = tid >> 3, tc8 = (tid & 7) * 8;
  #pragma unroll
  for (int i = 0; i < 2; i++) {
    int d = dr + i * 32;
    bf16x8 ov;
    #pragma unroll
    for (int j = 0; j < 8; j++) ov[j] = L[(tc8 + j) * 68 + d];
    *(bf16x8*)&vT[(size_t)(z * HD_ + d0 + d) * T_ + t0 + tc8] = ov;
  }
}

// ---------------- causal flash attention: 512 threads, 8 waves x 16 rows ----------
// r4/r6 structure (best measured: 82.6us): dbuf Ks/Vs + single barrier per K-tile,
// chunk-swizzled K/V layout, chunked P [16][48], setprio, defer-max.  Grid = 512
// (2 blocks/CU): x<256 heavy tile qt=15-p, x+256 light tile qt=p.
__device__ __forceinline__ int swz_w(int lane) {       // write slot for chunk (kt=lane>>2, ds=lane&3)
  return ((lane & 3) << 4) | ((lane >> 2) ^ ((lane & 3) << 1));
}
__device__ __forceinline__ int swz_r(int quad, int r16) { // read slot for (kt=r16, ds=quad)
  return (quad << 4) | (r16 ^ (quad << 1));
}

__device__ __forceinline__ void kv_prefetch8(const __bf16* kbase, const __bf16* vbase,
                                             int kt0, int wid, int lane,
                                             bf16x8 kreg[2], bf16x8 vreg[2]) {
  const int r4 = lane >> 2, c8 = (lane & 3) * 8;
  #pragma unroll
  for (int i = 0; i < 2; i++) {
    const int n = wid * 2 + i;   // K tile: kt4 = n>>2 (16 kt rows), d4 = n&3 (32 d cols)
    kreg[i] = *(const bf16x8*)&kbase[(size_t)(kt0 + (n >> 2) * 16 + r4) * HD_ + (n & 3) * 32 + c8];
    vreg[i] = *(const bf16x8*)&vbase[(size_t)((n >> 1) * 16 + r4) * T_ + kt0 + (n & 1) * 32 + c8];
  }
}

__device__ __forceinline__ void kv_commit8(__bf16* Ks, __bf16* Vs, int wid, int lane,
                                           const bf16x8 kreg[2], const bf16x8 vreg[2]) {
  const int slot = swz_w(lane);
  #pragma unroll
  for (int i = 0; i < 2; i++) {
    *(bf16x8*)(Ks + (wid * 2 + i) * 512 + slot * 8) = kreg[i];
    *(bf16x8*)(Vs + (wid * 2 + i) * 512 + slot * 8) = vreg[i];
  }
}

__global__ __launch_bounds__(512, 4) void flash(const __bf16* __restrict__ q,
                                                const __bf16* __restrict__ k,
                                                const __bf16* __restrict__ vT,
                                                __bf16* __restrict__ y) {
  __shared__ __align__(16) __bf16 Ks[2][64 * 128];  // dbuf x 16 swizzled tiles [16kt][32d]
  __shared__ __align__(16) __bf16 Vs[2][64 * 128];  // dbuf x 16 swizzled tiles [16d][32kt]
  __shared__ __align__(16) __bf16 Ps[8][16 * 48];   // per-wave P chunk scratch (32 cols)
  const int tid = threadIdx.x;
  const int wid = tid >> 6, lane = tid & 63, quad = lane >> 4, r16 = lane & 15;
  const int x   = blockIdx.x;
  const int p   = (x >> 5) & 7, hl = x & 31;
  const int qt  = (x < 256) ? (15 - p) : p;       // heavy half first; x and x+256 pair on one CU
  const int b = hl >> 4, h = hl & 15, hk = h >> 2;

  const __bf16* kbase = k  + (size_t)(b * KVH_ + hk) * T_ * HD_;
  const __bf16* vbase = vT + (size_t)(b * KVH_ + hk) * HD_ * T_;
  __bf16* Pw = Ps[wid];
  const float sc = 0.08838834764831845f;  // 1/sqrt(128)
  const float NEG = -__builtin_inff();
  bf16x8 ones;
  #pragma unroll
  for (int i = 0; i < 8; i++) ones[i] = (__bf16)1.0f;

  const int nt = 2 * (qt + 1);
  const int r0 = qt * 128 + wid * 16;   // this wave's 16 q-rows

  const __bf16* qrow = q + ((size_t)(b * NH_ + h) * T_ + r0 + r16) * HD_;
  bf16x8 qf[4];
  #pragma unroll
  for (int kb = 0; kb < 4; kb++) qf[kb] = *(const bf16x8*)&qrow[kb * 32 + quad * 8];

  floatx4 o[8], ol = (floatx4){0.f, 0.f, 0.f, 0.f};
  #pragma unroll
  for (int j = 0; j < 8; j++) o[j] = (floatx4){0.f, 0.f, 0.f, 0.f};
  float m_r[4] = {NEG, NEG, NEG, NEG};

  bf16x8 kreg[2], vreg[2];
  kv_prefetch8(kbase, vbase, 0, wid, lane, kreg, vreg);
  kv_commit8(&Ks[0][0], &Vs[0][0], wid, lane, kreg, vreg);
  if (nt > 1) kv_prefetch8(kbase, vbase, 64, wid, lane, kreg, vreg);
  __syncthreads();                        // tile 0 visible

  #pragma unroll 1
  for (int it = 0; it < nt; ++it) {
    if (it + 1 < nt) {
      // buf[(it+1)&1]'s previous readers (tile it-1) finished at the barrier
      // ending iter it-1, so this commit is race-free.
      kv_commit8(&Ks[(it + 1) & 1][0], &Vs[(it + 1) & 1][0], wid, lane, kreg, vreg);
      if (it + 2 < nt) kv_prefetch8(kbase, vbase, (it + 2) * 64, wid, lane, kreg, vreg);
    }

    const int kt0 = it * 64;
    const __bf16* Kb = &Ks[it & 1][0];
    const __bf16* Vb = &Vs[it & 1][0];
    if (kt0 <= r0 + 15) {                 // wave-uniform causal skip (no barriers inside)
      floatx4 s[4];
      #pragma unroll
      for (int cb = 0; cb < 4; cb++) s[cb] = (floatx4){0.f, 0.f, 0.f, 0.f};
      __builtin_amdgcn_s_setprio(1);
      #pragma unroll
      for (int kb = 0; kb < 4; kb++)
        #pragma unroll
        for (int cb = 0; cb < 4; cb++) {
          bf16x8 kf = *(const bf16x8*)&Kb[(cb * 4 + kb) * 512 + swz_r(quad, r16) * 8];
          s[cb] = __builtin_amdgcn_mfma_f32_16x16x32_bf16(qf[kb], kf, s[cb], 0, 0, 0);
        }
      __builtin_amdgcn_s_setprio(0);

      // scale + causal mask in place
      const bool needmask = (kt0 + 63 > r0);  // wave-uniform
      #pragma unroll
      for (int reg = 0; reg < 4; reg++) {
        const int rowq = r0 + quad * 4 + reg;
        s[0][reg] *= sc; s[1][reg] *= sc; s[2][reg] *= sc; s[3][reg] *= sc;
        if (needmask) {
          if (kt0 +      r16 > rowq) s[0][reg] = NEG;
          if (kt0 + 16 + r16 > rowq) s[1][reg] = NEG;
          if (kt0 + 32 + r16 > rowq) s[2][reg] = NEG;
          if (kt0 + 48 + r16 > rowq) s[3][reg] = NEG;
        }
      }
      // per-row max + running-max bookkeeping
      float mx[4], mnew[4];
      #pragma unroll
      for (int reg = 0; reg < 4; reg++) {
        float m0 = fmaxf(fmaxf(s[0][reg], s[1][reg]), fmaxf(s[2][reg], s[3][reg]));
        #pragma unroll
        for (int off = 8; off; off >>= 1) m0 = fmaxf(m0, __shfl_xor(m0, off));
        mx[reg] = m0;
        mnew[reg] = fmaxf(m_r[reg], m0);
      }
      // T13 defer-max: if no row grew its max by >8, keep old m (P bounded by e^8)
      float growth = fmaxf(fmaxf(mx[0] - m_r[0], mx[1] - m_r[1]),
                           fmaxf(mx[2] - m_r[2], mx[3] - m_r[3]));
      if (!__all(growth <= 8.0f)) {
        #pragma unroll
        for (int reg = 0; reg < 4; reg++) {
          float a = __expf(m_r[reg] - mnew[reg]);
          m_r[reg] = mnew[reg];
          ol[reg] *= a;
          #pragma unroll
          for (int j = 0; j < 8; j++) o[j][reg] *= a;
        }
      }
      // two 32-col chunks: exp -> Pw -> P-frag -> rowsum + PV MFMAs
      #pragma unroll
      for (int c = 0; c < 2; c++) {
        #pragma unroll
        for (int reg = 0; reg < 4; reg++) {
          const int prow = quad * 4 + reg;
          Pw[prow * 48 +      r16] = (__bf16)__expf(s[2 * c    ][reg] - m_r[reg]);
          Pw[prow * 48 + 16 + r16] = (__bf16)__expf(s[2 * c + 1][reg] - m_r[reg]);
        }
        __asm__ volatile("" ::: "memory");  // wave-private P: writes before reads
        bf16x8 pf = *(const bf16x8*)&Pw[r16 * 48 + quad * 8];
        __builtin_amdgcn_s_setprio(1);
        ol = __builtin_amdgcn_mfma_f32_16x16x32_bf16(pf, ones, ol, 0, 0, 0);
        #pragma unroll
        for (int j = 0; j < 8; j++) {
          bf16x8 vf = *(const bf16x8*)&Vb[(j * 2 + c) * 512 + swz_r(quad, r16) * 8];
          o[j] = __builtin_amdgcn_mfma_f32_16x16x32_bf16(pf, vf, o[j], 0, 0, 0);
        }
        __builtin_amdgcn_s_setprio(0);
        __asm__ volatile("" ::: "memory");  // keep chunk1 writes after chunk0 reads
      }
    }
    __syncthreads();                      // seals tile it reads; publishes tile it+1
  }

  #pragma unroll
  for (int reg = 0; reg < 4; reg++) {
    int trow = r0 + quad * 4 + reg;
    float inv = 1.0f / ol[reg];  // rowsum identical across lanes (ones-MFMA trick)
    __bf16* yr = y + ((size_t)(b * T_) + trow) * C_ + h * HD_;
    #pragma unroll
    for (int j = 0; j < 8; j++) yr[j * 16 + r16] = (__bf16)(o[j][reg] * inv);
  }
}

extern "C" void kernel_launch(void* const* d_in, const int* in_sizes, int n_in,
                              void* d_out, int out_size, void* d_ws, size_t ws_size,
                              hipStream_t stream) {
  const float* x     = (const float*)d_in[0];
  const float* wqkv  = (const float*)d_in[1];
  const float* wproj = (const float*)d_in[2];
  const float* qw    = (const float*)d_in[3];
  const float* kw    = (const float*)d_in[4];
  const float* fc    = (const float*)d_in[5];
  const float* fs    = (const float*)d_in[6];
  float* out = (float*)d_out;

  char* w = (char*)d_ws;
  __bf16* xb     = (__bf16*)w; w += (size_t)M_ * C_ * 2;
  __bf16* wqkvb  = (__bf16*)w; w += (size_t)QKV_ * C_ * 2;
  __bf16* wprojb = (__bf16*)w; w += (size_t)C_ * C_ * 2;
  __bf16* qkv    = (__bf16*)w; w += (size_t)M_ * QKV_ * 2;
  __bf16* qn     = (__bf16*)w; w += (size_t)B_ * NH_ * T_ * HD_ * 2;
  __bf16* kn     = (__bf16*)w; w += (size_t)B_ * KVH_ * T_ * HD_ * 2;
  __bf16* vT     = (__bf16*)w; w += (size_t)B_ * KVH_ * T_ * HD_ * 2;
  __bf16* ybf    = (__bf16*)w; w += (size_t)M_ * C_ * 2;

  const int n0 = M_ * C_ / 4, n1 = QKV_ * C_ / 4, n2 = C_ * C_ / 4;
  cvt3<<<(n0 + n1 + n2 + 255) / 256, 256, 0, stream>>>(x, xb, n0, wqkv, wqkvb, n1, wproj, wprojb, n2);

  gemm_cnt<__bf16><<<dim3(QKV_ / 128, M_ / 128), 256, 0, stream>>>(xb, wqkvb, qkv, QKV_, C_);
  ropevt<<<M_ / 4 + (T_ / 64) * (HD_ / 64) * (B_ * KVH_), 256, 0, stream>>>(qkv, qw, kw, fc, fs, qn, kn, vT);
  flash<<<dim3(512), 512, 0, stream>>>(qn, kn, vT, ybf);
  gemm_cnt<float><<<dim3(C_ / 128, M_ / 128), 256, 0, stream>>>(ybf, wprojb, out, C_, C_);
}

// Round 8
// 307.157 us; speedup vs baseline: 1.0658x; 1.0288x over previous
//
#include <hip/hip_runtime.h>
#include <hip/hip_bf16.h>

#define B_    2
#define T_    2048
#define C_    2048
#define NH_   16
#define KVH_  4
#define HD_   128
#define QKV_  3072
#define M_    4096

typedef float  floatx4 __attribute__((ext_vector_type(4)));
typedef __bf16 bf16x8  __attribute__((ext_vector_type(8)));
typedef __bf16 bf16x4  __attribute__((ext_vector_type(4)));
typedef __bf16 bf16x2  __attribute__((ext_vector_type(2)));

typedef const __attribute__((address_space(1))) void* gas_t;
typedef __attribute__((address_space(3))) void*       las_t;
__device__ __forceinline__ void gl_lds16(const void* g, void* l) {
  __builtin_amdgcn_global_load_lds((gas_t)g, (las_t)l, 16, 0, 0);
}

// ---------------- fp32 -> bf16 conversion, all three tensors in one launch ----------
__global__ __launch_bounds__(256) void cvt3(const float* __restrict__ s0, __bf16* __restrict__ d0, int n0,
                                            const float* __restrict__ s1, __bf16* __restrict__ d1, int n1,
                                            const float* __restrict__ s2, __bf16* __restrict__ d2, int n2) {
  int i = blockIdx.x * blockDim.x + threadIdx.x;
  const float* s; __bf16* d;
  if (i < n0) { s = s0; d = d0; }
  else {
    i -= n0;
    if (i < n1) { s = s1; d = d1; }
    else { i -= n1; if (i >= n2) return; s = s2; d = d2; }
  }
  float4 f = ((const float4*)s)[i];
  bf16x4 o = { (__bf16)f.x, (__bf16)f.y, (__bf16)f.z, (__bf16)f.w };
  ((bf16x4*)d)[i] = o;
}

// ---------------- counted-vmcnt 128x128 GEMM: C = A[M][K] * B[N][K]^T --------------
// (unchanged from r7 -- measured ~+6us over m97 with ropevt fusion)
template <typename OutT>
__global__ __launch_bounds__(256, 2) void gemm_cnt(const __bf16* __restrict__ A,
                                                   const __bf16* __restrict__ Bm,
                                                   OutT* __restrict__ Cc,
                                                   int N, int K) {
  __shared__ __align__(16) __bf16 As[2][128 * 64];
  __shared__ __align__(16) __bf16 Bs[2][128 * 64];
  const int tid  = threadIdx.x;
  const int wid  = tid >> 6, lane = tid & 63, quad = lane >> 4, r16 = lane & 15;
  const int bm   = blockIdx.y * 128, bn = blockIdx.x * 128;
  const int wm   = (wid >> 1) * 64, wn = (wid & 1) * 64;
  const int srow = tid >> 3;                       // 0..31 (row within 32-row pass)
  const int clog = (tid & 7) ^ (srow & 7);         // pre-swizzled source k-chunk
  const __bf16* aR = A  + (size_t)(bm + srow) * K + clog * 8;
  const __bf16* bR = Bm + (size_t)(bn + srow) * K + clog * 8;
  const int nt = K >> 6;

  floatx4 acc[4][4];
  #pragma unroll
  for (int i = 0; i < 4; i++)
    #pragma unroll
    for (int j = 0; j < 4; j++) acc[i][j] = (floatx4){0.f, 0.f, 0.f, 0.f};

  auto stage = [&](int s, int k0) {   // 8 gl_lds16 / thread (4 A + 4 B)
    #pragma unroll
    for (int p = 0; p < 4; p++) {
      gl_lds16(aR + (size_t)(p * 32) * K + k0, &As[s][(p * 32 + wid * 8) * 64]);
      gl_lds16(bR + (size_t)(p * 32) * K + k0, &Bs[s][(p * 32 + wid * 8) * 64]);
    }
  };

  stage(0, 0);                                     // prologue: tile 0 in flight

  #pragma unroll 1
  for (int j = 0; j < nt; ++j) {
    if (j + 1 < nt) {
      stage((j + 1) & 1, (j + 1) << 6);            // issue next tile (8 loads)
      asm volatile("s_waitcnt vmcnt(8)" ::: "memory");  // tile j done, j+1 flying
    } else {
      asm volatile("s_waitcnt vmcnt(0)" ::: "memory");  // last tile: drain
    }
    __builtin_amdgcn_s_barrier();                  // all waves' tile-j loads visible
    asm volatile("" ::: "memory");

    const __bf16* Ab = As[j & 1];
    const __bf16* Bb = Bs[j & 1];
    #pragma unroll
    for (int hf = 0; hf < 2; hf++) {
      const int xo = (((hf << 2) + quad) ^ (r16 & 7)) << 3;  // swizzled chunk offset
      bf16x8 af[4], bfr[4];
      #pragma unroll
      for (int i = 0; i < 4; i++) af[i]  = *(const bf16x8*)&Ab[(wm + i * 16 + r16) * 64 + xo];
      #pragma unroll
      for (int i = 0; i < 4; i++) bfr[i] = *(const bf16x8*)&Bb[(wn + i * 16 + r16) * 64 + xo];
      __builtin_amdgcn_s_setprio(1);
      #pragma unroll
      for (int i = 0; i < 4; i++)
        #pragma unroll
        for (int jj = 0; jj < 4; jj++)
          acc[i][jj] = __builtin_amdgcn_mfma_f32_16x16x32_bf16(af[i], bfr[jj], acc[i][jj], 0, 0, 0);
      __builtin_amdgcn_s_setprio(0);
    }
    asm volatile("" ::: "memory");
    __builtin_amdgcn_s_barrier();                  // seal buf[j&1] reads (reused at j+2)
    asm volatile("" ::: "memory");
  }

  #pragma unroll
  for (int i = 0; i < 4; i++) {
    #pragma unroll
    for (int reg = 0; reg < 4; reg++) {
      int row = bm + wm + i * 16 + quad * 4 + reg;
      OutT* crow = Cc + (size_t)row * N + bn + wn;
      #pragma unroll
      for (int j = 0; j < 4; j++) crow[j * 16 + r16] = (OutT)acc[i][j][reg];
    }
  }
}

// ---------------- fused RoPE+RMSNorm (blocks 0..1023) + V transpose (1024..1535) ----
__global__ __launch_bounds__(256) void ropevt(const __bf16* __restrict__ qkv,
                                              const float* __restrict__ qw,
                                              const float* __restrict__ kw,
                                              const float* __restrict__ fc,
                                              const float* __restrict__ fs,
                                              __bf16* __restrict__ qn,
                                              __bf16* __restrict__ kn,
                                              __bf16* __restrict__ vT) {
  __shared__ __bf16 L[64 * 68];
  const int tid = threadIdx.x;
  if (blockIdx.x < M_ / 4) {
    const int wid  = tid >> 6, lane = tid & 63;
    const int row  = blockIdx.x * 4 + wid;        // b*T + t
    const int b    = row >> 11, t = row & (T_ - 1);
    const float cs = fc[t * 64 + lane], sn = fs[t * 64 + lane];
    const __bf16* base = qkv + (size_t)row * QKV_;

    #pragma unroll 2
    for (int h = 0; h < NH_; h++) {
      bf16x2 ab = *(const bf16x2*)(base + h * HD_ + 2 * lane);
      float ax = (float)ab[0], ay = (float)ab[1];
      float oa = ax * cs - ay * sn;
      float ob = ax * sn + ay * cs;
      float ss = oa * oa + ob * ob;
      #pragma unroll
      for (int off = 32; off; off >>= 1) ss += __shfl_xor(ss, off);
      float rinv = rsqrtf(ss * (1.0f / HD_) + 1e-6f);
      bf16x2 o = { (__bf16)(oa * rinv * qw[2 * lane]), (__bf16)(ob * rinv * qw[2 * lane + 1]) };
      *(bf16x2*)&qn[(size_t)((b * NH_ + h) * T_ + t) * HD_ + 2 * lane] = o;
    }
    #pragma unroll 2
    for (int h = 0; h < KVH_; h++) {
      bf16x2 ab = *(const bf16x2*)(base + C_ + h * HD_ + 2 * lane);
      float ax = (float)ab[0], ay = (float)ab[1];
      float oa = ax * cs - ay * sn;
      float ob = ax * sn + ay * cs;
      float ss = oa * oa + ob * ob;
      #pragma unroll
      for (int off = 32; off; off >>= 1) ss += __shfl_xor(ss, off);
      float rinv = rsqrtf(ss * (1.0f / HD_) + 1e-6f);
      bf16x2 o = { (__bf16)(oa * rinv * kw[2 * lane]), (__bf16)(ob * rinv * kw[2 * lane + 1]) };
      *(bf16x2*)&kn[(size_t)((b * KVH_ + h) * T_ + t) * HD_ + 2 * lane] = o;
    }
    return;
  }
  const int idx = blockIdx.x - M_ / 4;
  const int t0 = (idx & 31) * 64;
  const int d0 = ((idx >> 5) & 1) * 64;
  const int z  = idx >> 6;              // b*KVH + hk
  const int b  = z >> 2, hk = z & 3;
  const int srcc = C_ + KVH_ * HD_ + hk * HD_ + d0;
  const int rr = tid >> 4, c4 = (tid & 15) * 4;
  #pragma unroll
  for (int i = 0; i < 4; i++) {
    int t = rr + i * 16;
    bf16x4 f = *(const bf16x4*)&qkv[(size_t)(b * T_ + t0 + t) * QKV_ + srcc + c4];
    *(bf16x4*)&L[t * 68 + c4] = f;
  }
  __syncthreads();
  const int dr = tid >> 3, tc8 = (tid & 7) * 8;
  #pragma unroll
  for (int i = 0; i < 2; i++) {
    int d = dr + i * 32;
    bf16x8 ov;
    #pragma unroll
    for (int j = 0; j < 8; j++) ov[j] = L[(tc8 + j) * 68 + d];
    *(bf16x8*)&vT[(size_t)(z * HD_ + d0 + d) * T_ + t0 + tc8] = ov;
  }
}

// ---------------- causal flash attention: 256 threads, 4 waves x 16 rows ----------
// Round-8 restructure: r7's occupancy (~27% = 8.6 waves/CU) revealed the light
// twin block vanishes in the first ~6% of runtime -> heavy blocks run with only
// 2 waves/SIMD, leaving the serial QK->softmax->P->PV spine latency half-covered
// (6200 cy/iter vs ~1500 cy pipe work).  Fix: 64-row Q-tiles, 4 waves x 16 rows
// (per-wave math IDENTICAL to r7), grid = 1024 small blocks; LDS 38.9KB -> up to
// 4 blocks/CU, launch_bounds(256,3) -> 12-16 resident waves SUSTAINED.
// Balance is deterministic: q'(x) maps the 4 blocks {g,g+8,g+16,g+24} that land
// on one CU (x%256 round-robin) to q' = {31-s, 16+s, 15-s, s}: nt-sum = 66 for
// every s.  Heavy bands dispatch first.  Single-buffer K/V, r1-style
// barrier/commit/barrier/prefetch structure (convoys now covered by co-resident
// blocks).  Keeps: chunk-swizzled K/V, chunked P [16][48], setprio, defer-max.
__device__ __forceinline__ int swz_w(int lane) {       // write slot for chunk (kt=lane>>2, ds=lane&3)
  return ((lane & 3) << 4) | ((lane >> 2) ^ ((lane & 3) << 1));
}
__device__ __forceinline__ int swz_r(int quad, int r16) { // read slot for (kt=r16, ds=quad)
  return (quad << 4) | (r16 ^ (quad << 1));
}

__device__ __forceinline__ void kv_prefetch16(const __bf16* kbase, const __bf16* vbase,
                                              int kt0, int wid, int lane,
                                              bf16x8 kreg[4], bf16x8 vreg[4]) {
  const int r4 = lane >> 2, c8 = (lane & 3) * 8;
  #pragma unroll
  for (int i = 0; i < 4; i++) {
    const int n = wid * 4 + i;   // K tile: kt4 = n>>2 (16 kt rows), d4 = n&3 (32 d cols)
    kreg[i] = *(const bf16x8*)&kbase[(size_t)(kt0 + (n >> 2) * 16 + r4) * HD_ + (n & 3) * 32 + c8];
    vreg[i] = *(const bf16x8*)&vbase[(size_t)((n >> 1) * 16 + r4) * T_ + kt0 + (n & 1) * 32 + c8];
  }
}

__device__ __forceinline__ void kv_commit16(__bf16* Ks, __bf16* Vs, int wid, int lane,
                                            const bf16x8 kreg[4], const bf16x8 vreg[4]) {
  const int slot = swz_w(lane);
  #pragma unroll
  for (int i = 0; i < 4; i++) {
    *(bf16x8*)(Ks + (wid * 4 + i) * 512 + slot * 8) = kreg[i];
    *(bf16x8*)(Vs + (wid * 4 + i) * 512 + slot * 8) = vreg[i];
  }
}

__global__ __launch_bounds__(256, 3) void flash(const __bf16* __restrict__ q,
                                                const __bf16* __restrict__ k,
                                                const __bf16* __restrict__ vT,
                                                __bf16* __restrict__ y) {
  __shared__ __align__(16) __bf16 Ks[64 * 128];   // 16 swizzled tiles [16kt][32d]
  __shared__ __align__(16) __bf16 Vs[128 * 64];   // 16 swizzled tiles [16d][32kt]
  __shared__ __align__(16) __bf16 Ps[4][16 * 48]; // per-wave P chunk scratch (32 cols)
  const int tid = threadIdx.x;
  const int wid = tid >> 6, lane = tid & 63, quad = lane >> 4, r16 = lane & 15;
  const int x   = blockIdx.x;
  const int g   = x >> 5, bh = x & 31;
  const int sub = g & 7, band = g >> 3;
  // per-CU quadruple {31-s, 16+s, 15-s, s}: nt-sum 66 for every s; heavies first
  const int qp  = (band == 0) ? (31 - sub) : (band == 1) ? (16 + sub)
                : (band == 2) ? (15 - sub) : sub;
  const int b = bh >> 4, h = bh & 15, hk = h >> 2;

  const __bf16* kbase = k  + (size_t)(b * KVH_ + hk) * T_ * HD_;
  const __bf16* vbase = vT + (size_t)(b * KVH_ + hk) * HD_ * T_;
  __bf16* Pw = Ps[wid];
  const float sc = 0.08838834764831845f;  // 1/sqrt(128)
  const float NEG = -__builtin_inff();
  bf16x8 ones;
  #pragma unroll
  for (int i = 0; i < 8; i++) ones[i] = (__bf16)1.0f;

  const int nt = qp + 1;                 // K-tiles of 64 for a 64-row Q-tile
  const int r0 = qp * 64 + wid * 16;     // this wave's 16 q-rows

  const __bf16* qrow = q + ((size_t)(b * NH_ + h) * T_ + r0 + r16) * HD_;
  bf16x8 qf[4];
  #pragma unroll
  for (int kb = 0; kb < 4; kb++) qf[kb] = *(const bf16x8*)&qrow[kb * 32 + quad * 8];

  floatx4 o[8], ol = (floatx4){0.f, 0.f, 0.f, 0.f};
  #pragma unroll
  for (int j = 0; j < 8; j++) o[j] = (floatx4){0.f, 0.f, 0.f, 0.f};
  float m_r[4] = {NEG, NEG, NEG, NEG};

  bf16x8 kreg[4], vreg[4];
  kv_prefetch16(kbase, vbase, 0, wid, lane, kreg, vreg);

  #pragma unroll 1
  for (int it = 0; it < nt; ++it) {
    __syncthreads();                      // all waves done reading previous tile
    kv_commit16(Ks, Vs, wid, lane, kreg, vreg);
    __syncthreads();                      // tile it visible
    if (it + 1 < nt) kv_prefetch16(kbase, vbase, (it + 1) * 64, wid, lane, kreg, vreg);

    const int kt0 = it * 64;
    {
      floatx4 s[4];
      #pragma unroll
      for (int cb = 0; cb < 4; cb++) s[cb] = (floatx4){0.f, 0.f, 0.f, 0.f};
      __builtin_amdgcn_s_setprio(1);
      #pragma unroll
      for (int kb = 0; kb < 4; kb++)
        #pragma unroll
        for (int cb = 0; cb < 4; cb++) {
          bf16x8 kf = *(const bf16x8*)&Ks[(cb * 4 + kb) * 512 + swz_r(quad, r16) * 8];
          s[cb] = __builtin_amdgcn_mfma_f32_16x16x32_bf16(qf[kb], kf, s[cb], 0, 0, 0);
        }
      __builtin_amdgcn_s_setprio(0);

      // scale + causal mask in place
      const bool needmask = (kt0 + 63 > r0);  // wave-uniform (last tile only)
      #pragma unroll
      for (int reg = 0; reg < 4; reg++) {
        const int rowq = r0 + quad * 4 + reg;
        s[0][reg] *= sc; s[1][reg] *= sc; s[2][reg] *= sc; s[3][reg] *= sc;
        if (needmask) {
          if (kt0 +      r16 > rowq) s[0][reg] = NEG;
          if (kt0 + 16 + r16 > rowq) s[1][reg] = NEG;
          if (kt0 + 32 + r16 > rowq) s[2][reg] = NEG;
          if (kt0 + 48 + r16 > rowq) s[3][reg] = NEG;
        }
      }
      // per-row max + running-max bookkeeping
      float mx[4], mnew[4];
      #pragma unroll
      for (int reg = 0; reg < 4; reg++) {
        float m0 = fmaxf(fmaxf(s[0][reg], s[1][reg]), fmaxf(s[2][reg], s[3][reg]));
        #pragma unroll
        for (int off = 8; off; off >>= 1) m0 = fmaxf(m0, __shfl_xor(m0, off));
        mx[reg] = m0;
        mnew[reg] = fmaxf(m_r[reg], m0);
      }
      // T13 defer-max: if no row grew its max by >8, keep old m (P bounded by e^8)
      float growth = fmaxf(fmaxf(mx[0] - m_r[0], mx[1] - m_r[1]),
                           fmaxf(mx[2] - m_r[2], mx[3] - m_r[3]));
      if (!__all(growth <= 8.0f)) {
        #pragma unroll
        for (int reg = 0; reg < 4; reg++) {
          float a = __expf(m_r[reg] - mnew[reg]);
          m_r[reg] = mnew[reg];
          ol[reg] *= a;
          #pragma unroll
          for (int j = 0; j < 8; j++) o[j][reg] *= a;
        }
      }
      // two 32-col chunks: exp -> Pw -> P-frag -> rowsum + PV MFMAs
      #pragma unroll
      for (int c = 0; c < 2; c++) {
        #pragma unroll
        for (int reg = 0; reg < 4; reg++) {
          const int prow = quad * 4 + reg;
          Pw[prow * 48 +      r16] = (__bf16)__expf(s[2 * c    ][reg] - m_r[reg]);
          Pw[prow * 48 + 16 + r16] = (__bf16)__expf(s[2 * c + 1][reg] - m_r[reg]);
        }
        __asm__ volatile("" ::: "memory");  // wave-private P: writes before reads
        bf16x8 pf = *(const bf16x8*)&Pw[r16 * 48 + quad * 8];
        __builtin_amdgcn_s_setprio(1);
        ol = __builtin_amdgcn_mfma_f32_16x16x32_bf16(pf, ones, ol, 0, 0, 0);
        #pragma unroll
        for (int j = 0; j < 8; j++) {
          bf16x8 vf = *(const bf16x8*)&Vs[(j * 2 + c) * 512 + swz_r(quad, r16) * 8];
          o[j] = __builtin_amdgcn_mfma_f32_16x16x32_bf16(pf, vf, o[j], 0, 0, 0);
        }
        __builtin_amdgcn_s_setprio(0);
        __asm__ volatile("" ::: "memory");  // keep chunk1 writes after chunk0 reads
      }
    }
  }

  #pragma unroll
  for (int reg = 0; reg < 4; reg++) {
    int trow = r0 + quad * 4 + reg;
    float inv = 1.0f / ol[reg];  // rowsum identical across lanes (ones-MFMA trick)
    __bf16* yr = y + ((size_t)(b * T_) + trow) * C_ + h * HD_;
    #pragma unroll
    for (int j = 0; j < 8; j++) yr[j * 16 + r16] = (__bf16)(o[j][reg] * inv);
  }
}

extern "C" void kernel_launch(void* const* d_in, const int* in_sizes, int n_in,
                              void* d_out, int out_size, void* d_ws, size_t ws_size,
                              hipStream_t stream) {
  const float* x     = (const float*)d_in[0];
  const float* wqkv  = (const float*)d_in[1];
  const float* wproj = (const float*)d_in[2];
  const float* qw    = (const float*)d_in[3];
  const float* kw    = (const float*)d_in[4];
  const float* fc    = (const float*)d_in[5];
  const float* fs    = (const float*)d_in[6];
  float* out = (float*)d_out;

  char* w = (char*)d_ws;
  __bf16* xb     = (__bf16*)w; w += (size_t)M_ * C_ * 2;
  __bf16* wqkvb  = (__bf16*)w; w += (size_t)QKV_ * C_ * 2;
  __bf16* wprojb = (__bf16*)w; w += (size_t)C_ * C_ * 2;
  __bf16* qkv    = (__bf16*)w; w += (size_t)M_ * QKV_ * 2;
  __bf16* qn     = (__bf16*)w; w += (size_t)B_ * NH_ * T_ * HD_ * 2;
  __bf16* kn     = (__bf16*)w; w += (size_t)B_ * KVH_ * T_ * HD_ * 2;
  __bf16* vT     = (__bf16*)w; w += (size_t)B_ * KVH_ * T_ * HD_ * 2;
  __bf16* ybf    = (__bf16*)w; w += (size_t)M_ * C_ * 2;

  const int n0 = M_ * C_ / 4, n1 = QKV_ * C_ / 4, n2 = C_ * C_ / 4;
  cvt3<<<(n0 + n1 + n2 + 255) / 256, 256, 0, stream>>>(x, xb, n0, wqkv, wqkvb, n1, wproj, wprojb, n2);

  gemm_cnt<__bf16><<<dim3(QKV_ / 128, M_ / 128), 256, 0, stream>>>(xb, wqkvb, qkv, QKV_, C_);
  ropevt<<<M_ / 4 + (T_ / 64) * (HD_ / 64) * (B_ * KVH_), 256, 0, stream>>>(qkv, qw, kw, fc, fs, qn, kn, vT);
  flash<<<dim3(1024), 256, 0, stream>>>(qn, kn, vT, ybf);
  gemm_cnt<float><<<dim3(C_ / 128, M_ / 128), 256, 0, stream>>>(ybf, wprojb, out, C_, C_);
}